// Round 6
// baseline (144.556 us; speedup 1.0000x reference)
//
#include <hip/hip_runtime.h>
#include <hip/hip_fp16.h>

// Bilinear grid-sample on v[B,C,H,W] f32, per-pixel random query coords.
// Round 6: gathers made L2-resident with real margin.
//  - vt split into FOUR quarter-channel tensors [B][HW][4ch] f16 (8 B/px),
//    one gather pass per quarter: per-XCD working set = 2 MiB = half of L2
//    (round 5's 4 MiB = exactly-L2 left no room for store pollution).
//  - batch-per-XCD swizzle (b = blockIdx.x & 7).
//  - row-pair loads: corners (y,x0),(y,x1) = one contiguous 16 B load
//    (8B-aligned) + lane select for the x-clamp edge. 2 random loads per
//    query per pass; 8 total = the gathered-bytes minimum.
//  - nt hints on all single-touch streams.

#define BATCH 8
#define CHAN  16
#define HEIGHT 512
#define WIDTH  512
#define HW (HEIGHT * WIDTH)
#define QCH 4                       // channels per quarter
#define NQ  4                       // number of quarters
#define QELEMS ((size_t)BATCH * HW * QCH)   // halves per quarter tensor
#define BLOCKS_PER_BATCH (HW / 256) // 1024

typedef unsigned int u32;
// honest 8-byte alignment for the 16 B row-pair load (px pairs start at
// arbitrary x -> 8 B granularity)
typedef __attribute__((ext_vector_type(4), aligned(8))) u32 u32x4a;

__device__ __forceinline__ float2 h2_to_f2(u32 u) {
    const __half2 h = __builtin_bit_cast(__half2, u);
    return __half22float2(h);
}

// --- pass 1: BCHW f32 -> four [B][HW][4] f16 quarter tensors ----------------
__global__ __launch_bounds__(256) void transpose_quarters_f16(
    const float* __restrict__ v, __half* __restrict__ vt)
{
    const int blk = blockIdx.x;
    const int b = blk & 7;
    const int p = (blk >> 3) * 256 + threadIdx.x;
    const int tid = b * HW + p;

    const float* src = v + (size_t)b * CHAN * HW + p;

    __half2 d[8];
#pragma unroll
    for (int j = 0; j < 8; ++j) {
        const float lo = __builtin_nontemporal_load(&src[(size_t)(2 * j + 0) * HW]);
        const float hi = __builtin_nontemporal_load(&src[(size_t)(2 * j + 1) * HW]);
        d[j] = __floats2half2_rn(lo, hi);
    }

#pragma unroll
    for (int q = 0; q < NQ; ++q)
        *(uint2*)(vt + q * QELEMS + (size_t)tid * QCH) = *(const uint2*)&d[2 * q];
}

// --- passes 2..5: gather 4 channels from one quarter tensor -----------------
__global__ __launch_bounds__(256) void interp2_quarter(
    const __half* __restrict__ vq,    // [B][HW][4] f16
    const float* __restrict__ xq,
    const float* __restrict__ yq,
    float* __restrict__ out,          // [B][CHAN][HW]
    int c0)                           // first output channel of this quarter
{
    const int blk = blockIdx.x;
    const int b = blk & 7;            // batch == XCD (round-robin dispatch)
    const int p = (blk >> 3) * 256 + threadIdx.x;
    const int qidx = b * HW + p;

    const float xqv = __builtin_nontemporal_load(&xq[qidx]);
    const float yqv = __builtin_nontemporal_load(&yq[qidx]);

    const bool invalid = (xqv < 0.0f) | (xqv >= (float)WIDTH) |
                         (yqv < 0.0f) | (yqv >= (float)HEIGHT);

    int x0 = (int)floorf(xqv);
    int y0 = (int)floorf(yqv);
    x0 = min(max(x0, 0), WIDTH - 1);
    y0 = min(max(y0, 0), HEIGHT - 1);
    const int y1 = min(y0 + 1, HEIGHT - 1);

    const float dx = xqv - (float)x0;
    const float dy = yqv - (float)y0;

    float w00 = (1.0f - dy) * (1.0f - dx);
    float w01 = (1.0f - dy) * dx;
    float w10 = dy * (1.0f - dx);
    float w11 = dy * dx;
    if (invalid) { w00 = 0.0f; w01 = 0.0f; w10 = 0.0f; w11 = 0.0f; }

    // row-pair base: covers pixels bx, bx+1. If x0==W-1 both corners are the
    // clamped px W-1, which is the HI half of the pair at bx=W-2.
    const int bx = min(x0, WIDTH - 2);
    const bool xlo = (x0 == bx);

    const size_t bbase = (size_t)b * HW;
    const u32x4a r0 = *(const u32x4a*)(vq + (bbase + (size_t)y0 * WIDTH + bx) * QCH);
    const u32x4a r1 = *(const u32x4a*)(vq + (bbase + (size_t)y1 * WIDTH + bx) * QCH);

    // corner 00 = left or right px of r0 depending on clamp; corner 01 is
    // always the right px (x1 = min(x0+1, W-1) = bx+1 in both cases).
    const u32 c00a = xlo ? r0.x : r0.z, c00b = xlo ? r0.y : r0.w;
    const u32 c10a = xlo ? r1.x : r1.z, c10b = xlo ? r1.y : r1.w;

    float acc[QCH];
    {
        float2 f;
        f = h2_to_f2(c00a); acc[0]  = w00 * f.x; acc[1]  = w00 * f.y;
        f = h2_to_f2(c00b); acc[2]  = w00 * f.x; acc[3]  = w00 * f.y;
        f = h2_to_f2(r0.z); acc[0] += w01 * f.x; acc[1] += w01 * f.y;
        f = h2_to_f2(r0.w); acc[2] += w01 * f.x; acc[3] += w01 * f.y;
        f = h2_to_f2(c10a); acc[0] += w10 * f.x; acc[1] += w10 * f.y;
        f = h2_to_f2(c10b); acc[2] += w10 * f.x; acc[3] += w10 * f.y;
        f = h2_to_f2(r1.z); acc[0] += w11 * f.x; acc[1] += w11 * f.y;
        f = h2_to_f2(r1.w); acc[2] += w11 * f.x; acc[3] += w11 * f.y;
    }

    const size_t obase = (size_t)b * CHAN * HW + (size_t)c0 * HW + p;
#pragma unroll
    for (int c = 0; c < QCH; ++c)
        __builtin_nontemporal_store(acc[c], &out[obase + (size_t)c * HW]);
}

// --- fallback (BCHW direct) if ws too small --------------------------------
__global__ __launch_bounds__(256) void interp2_bchw(
    const float* __restrict__ v,
    const float* __restrict__ xq,
    const float* __restrict__ yq,
    float* __restrict__ out)
{
    const int tid = blockIdx.x * blockDim.x + threadIdx.x;
    if (tid >= BATCH * HW) return;

    const int b   = tid / HW;
    const int pix = tid - b * HW;

    const float xqv = xq[tid];
    const float yqv = yq[tid];
    const bool invalid = (xqv < 0.0f) | (xqv >= (float)WIDTH) |
                         (yqv < 0.0f) | (yqv >= (float)HEIGHT);

    int x0 = (int)floorf(xqv);
    int y0 = (int)floorf(yqv);
    x0 = min(max(x0, 0), WIDTH - 1);
    y0 = min(max(y0, 0), HEIGHT - 1);
    const int x1 = min(x0 + 1, WIDTH - 1);
    const int y1 = min(y0 + 1, HEIGHT - 1);

    const float dx = xqv - (float)x0;
    const float dy = yqv - (float)y0;
    float w00 = (1.0f - dy) * (1.0f - dx);
    float w01 = (1.0f - dy) * dx;
    float w10 = dy * (1.0f - dx);
    float w11 = dy * dx;
    if (invalid) { w00 = 0.0f; w01 = 0.0f; w10 = 0.0f; w11 = 0.0f; }

    const int off00 = y0 * WIDTH + x0;
    const int off01 = y0 * WIDTH + x1;
    const int off10 = y1 * WIDTH + x0;
    const int off11 = y1 * WIDTH + x1;

    const int vbase = b * CHAN * HW;
    const int obase = vbase + pix;
#pragma unroll
    for (int c = 0; c < CHAN; ++c) {
        const int cb = vbase + c * HW;
        out[obase + c * HW] = v[cb + off00] * w00 + v[cb + off01] * w01 +
                              v[cb + off10] * w10 + v[cb + off11] * w11;
    }
}

extern "C" void kernel_launch(void* const* d_in, const int* in_sizes, int n_in,
                              void* d_out, int out_size, void* d_ws, size_t ws_size,
                              hipStream_t stream) {
    const float* v  = (const float*)d_in[0];
    const float* xq = (const float*)d_in[1];
    const float* yq = (const float*)d_in[2];
    float* out = (float*)d_out;

    const int grid = BATCH * BLOCKS_PER_BATCH;   // 8192 blocks, 256 thr
    const size_t vt_bytes = NQ * QELEMS * sizeof(__half);   // 64 MiB

    if (ws_size >= vt_bytes) {
        __half* vt = (__half*)d_ws;
        transpose_quarters_f16<<<grid, 256, 0, stream>>>(v, vt);
#pragma unroll
        for (int q = 0; q < NQ; ++q)
            interp2_quarter<<<grid, 256, 0, stream>>>(vt + q * QELEMS, xq, yq, out, q * QCH);
    } else {
        const int npix = BATCH * HW;
        interp2_bchw<<<(npix + 255) / 256, 256, 0, stream>>>(v, xq, yq, out);
    }
}

// Round 8
// 138.981 us; speedup vs baseline: 1.0401x; 1.0401x over previous
//
#include <hip/hip_runtime.h>
#include <hip/hip_fp16.h>

// Bilinear grid-sample on v[B,C,H,W] f32, per-pixel random query coords.
// Round 8 (= round 7 with compile fix): round-4 single-gather structure plus:
//  - vt stores in transpose are NON-TEMPORAL (write-through): avoid dirty
//    cross-XCD L2 lines; let the 256 MiB memory-side L3 serve gather misses.
//  - gather issues all 8 corner loads before any arithmetic (explicit MLP).
// nt builtins need clang ext_vector types, not HIP_vector_type uint4.

#define BATCH 8
#define CHAN  16
#define HEIGHT 512
#define WIDTH  512
#define HW (HEIGHT * WIDTH)

typedef __attribute__((ext_vector_type(4))) unsigned int u32x4;

// --- pass 1: BCHW f32 -> BHWC f16 ------------------------------------------
__global__ __launch_bounds__(256) void transpose_bchw2bhwc_f16(
    const float* __restrict__ v, __half* __restrict__ vt)
{
    const int tid = blockIdx.x * blockDim.x + threadIdx.x;
    if (tid >= BATCH * HW) return;
    const int b = tid / HW;
    const int p = tid - b * HW;

    const float* src = v + (size_t)b * CHAN * HW + p;

    __half2 d[8];
#pragma unroll
    for (int j = 0; j < 8; ++j) {
        const float lo = __builtin_nontemporal_load(&src[(size_t)(2 * j + 0) * HW]);
        const float hi = __builtin_nontemporal_load(&src[(size_t)(2 * j + 1) * HW]);
        d[j] = __floats2half2_rn(lo, hi);
    }

    u32x4* dst = (u32x4*)(vt + (size_t)tid * CHAN);
    __builtin_nontemporal_store(*(const u32x4*)&d[0], &dst[0]);
    __builtin_nontemporal_store(*(const u32x4*)&d[4], &dst[1]);
}

// --- pass 2: gather + bilinear in f16 BHWC, f32 math, write BCHW -----------
__global__ __launch_bounds__(256) void interp2_bhwc_f16(
    const __half* __restrict__ vt,
    const float* __restrict__ xq,
    const float* __restrict__ yq,
    float* __restrict__ out)
{
    const int tid = blockIdx.x * blockDim.x + threadIdx.x;
    if (tid >= BATCH * HW) return;

    const int b   = tid / HW;
    const int pix = tid - b * HW;

    const float xqv = __builtin_nontemporal_load(&xq[tid]);
    const float yqv = __builtin_nontemporal_load(&yq[tid]);

    const bool invalid = (xqv < 0.0f) | (xqv >= (float)WIDTH) |
                         (yqv < 0.0f) | (yqv >= (float)HEIGHT);

    int x0 = (int)floorf(xqv);
    int y0 = (int)floorf(yqv);
    x0 = min(max(x0, 0), WIDTH - 1);
    y0 = min(max(y0, 0), HEIGHT - 1);
    const int x1 = min(x0 + 1, WIDTH - 1);
    const int y1 = min(y0 + 1, HEIGHT - 1);

    const float dx = xqv - (float)x0;
    const float dy = yqv - (float)y0;

    float w00 = (1.0f - dy) * (1.0f - dx);
    float w01 = (1.0f - dy) * dx;
    float w10 = dy * (1.0f - dx);
    float w11 = dy * dx;
    if (invalid) { w00 = 0.0f; w01 = 0.0f; w10 = 0.0f; w11 = 0.0f; }

    const size_t bbase = (size_t)b * HW;
    const __half* p00 = vt + (bbase + (size_t)y0 * WIDTH + x0) * CHAN;
    const __half* p01 = vt + (bbase + (size_t)y0 * WIDTH + x1) * CHAN;
    const __half* p10 = vt + (bbase + (size_t)y1 * WIDTH + x0) * CHAN;
    const __half* p11 = vt + (bbase + (size_t)y1 * WIDTH + x1) * CHAN;

    // issue all 8 loads before any math — explicit memory-level parallelism
    const u32x4 a00 = *(const u32x4*)p00;
    const u32x4 b00 = *(const u32x4*)(p00 + 8);
    const u32x4 a01 = *(const u32x4*)p01;
    const u32x4 b01 = *(const u32x4*)(p01 + 8);
    const u32x4 a10 = *(const u32x4*)p10;
    const u32x4 b10 = *(const u32x4*)(p10 + 8);
    const u32x4 a11 = *(const u32x4*)p11;
    const u32x4 b11 = *(const u32x4*)(p11 + 8);

    float acc[CHAN];
#pragma unroll
    for (int c = 0; c < CHAN; ++c) acc[c] = 0.0f;

    auto fma8 = [&](const u32x4& lo, const u32x4& hi, float w, float* a) {
#pragma unroll
        for (int j = 0; j < 4; ++j) {
            const __half2 h = __builtin_bit_cast(__half2, (unsigned int)lo[j]);
            const float2 f = __half22float2(h);
            a[2 * j + 0] += w * f.x;
            a[2 * j + 1] += w * f.y;
        }
#pragma unroll
        for (int j = 0; j < 4; ++j) {
            const __half2 h = __builtin_bit_cast(__half2, (unsigned int)hi[j]);
            const float2 f = __half22float2(h);
            a[8 + 2 * j + 0] += w * f.x;
            a[8 + 2 * j + 1] += w * f.y;
        }
    };

    fma8(a00, b00, w00, acc);
    fma8(a01, b01, w01, acc);
    fma8(a10, b10, w10, acc);
    fma8(a11, b11, w11, acc);

    // BCHW output: per-c stores coalesced across lanes; nt keeps the 131 MB
    // write stream from evicting vt in L2.
    const size_t obase = (size_t)b * CHAN * HW + pix;
#pragma unroll
    for (int c = 0; c < CHAN; ++c)
        __builtin_nontemporal_store(acc[c], &out[obase + (size_t)c * HW]);
}

// --- fallback (BCHW direct) if ws too small --------------------------------
__global__ __launch_bounds__(256) void interp2_bchw(
    const float* __restrict__ v,
    const float* __restrict__ xq,
    const float* __restrict__ yq,
    float* __restrict__ out)
{
    const int tid = blockIdx.x * blockDim.x + threadIdx.x;
    if (tid >= BATCH * HW) return;

    const int b   = tid / HW;
    const int pix = tid - b * HW;

    const float xqv = xq[tid];
    const float yqv = yq[tid];
    const bool invalid = (xqv < 0.0f) | (xqv >= (float)WIDTH) |
                         (yqv < 0.0f) | (yqv >= (float)HEIGHT);

    int x0 = (int)floorf(xqv);
    int y0 = (int)floorf(yqv);
    x0 = min(max(x0, 0), WIDTH - 1);
    y0 = min(max(y0, 0), HEIGHT - 1);
    const int x1 = min(x0 + 1, WIDTH - 1);
    const int y1 = min(y0 + 1, HEIGHT - 1);

    const float dx = xqv - (float)x0;
    const float dy = yqv - (float)y0;
    float w00 = (1.0f - dy) * (1.0f - dx);
    float w01 = (1.0f - dy) * dx;
    float w10 = dy * (1.0f - dx);
    float w11 = dy * dx;
    if (invalid) { w00 = 0.0f; w01 = 0.0f; w10 = 0.0f; w11 = 0.0f; }

    const int off00 = y0 * WIDTH + x0;
    const int off01 = y0 * WIDTH + x1;
    const int off10 = y1 * WIDTH + x0;
    const int off11 = y1 * WIDTH + x1;

    const int vbase = b * CHAN * HW;
    const int obase = vbase + pix;
#pragma unroll
    for (int c = 0; c < CHAN; ++c) {
        const int cb = vbase + c * HW;
        out[obase + c * HW] = v[cb + off00] * w00 + v[cb + off01] * w01 +
                              v[cb + off10] * w10 + v[cb + off11] * w11;
    }
}

extern "C" void kernel_launch(void* const* d_in, const int* in_sizes, int n_in,
                              void* d_out, int out_size, void* d_ws, size_t ws_size,
                              hipStream_t stream) {
    const float* v  = (const float*)d_in[0];
    const float* xq = (const float*)d_in[1];
    const float* yq = (const float*)d_in[2];
    float* out = (float*)d_out;

    const int npix = BATCH * HW;
    const int block = 256;
    const int grid = (npix + block - 1) / block;

    const size_t vt_bytes = (size_t)BATCH * HW * CHAN * sizeof(__half);  // 64 MiB
    if (ws_size >= vt_bytes) {
        __half* vt = (__half*)d_ws;
        transpose_bchw2bhwc_f16<<<grid, block, 0, stream>>>(v, vt);
        interp2_bhwc_f16<<<grid, block, 0, stream>>>(vt, xq, yq, out);
    } else {
        interp2_bchw<<<grid, block, 0, stream>>>(v, xq, yq, out);
    }
}

// Round 9
// 129.093 us; speedup vs baseline: 1.1198x; 1.0766x over previous
//
#include <hip/hip_runtime.h>
#include <hip/hip_fp16.h>

// Bilinear grid-sample on v[B,C,H,W] f32, per-pixel random query coords.
// Round 9: exact revert to the round-4 best (129.0 us).
//  - pass 1: BCHW f32 -> BHWC f16 (64 MiB) transpose; v reads nt, vt stores
//    REGULAR (the gather harvests L2 hits from transpose-warmed lines —
//    round-8 nt write-through cost +15% gather time).
//  - pass 2: one corner = 2x 16B loads from a 32 B/pixel record; coords nt;
//    out stores nt (131 MB single-touch stream must not evict vt from L2).
// Falsified across rounds 5-8: L2 batch-partitioning, channel-split passes,
// nt vt stores, explicit 8-load MLP. Gather runs at ~3.9 TB/s mixed
// random-line read + stream write = fabric efficiency for this pattern.

#define BATCH 8
#define CHAN  16
#define HEIGHT 512
#define WIDTH  512
#define HW (HEIGHT * WIDTH)

// --- pass 1: BCHW f32 -> BHWC f16 ------------------------------------------
__global__ __launch_bounds__(256) void transpose_bchw2bhwc_f16(
    const float* __restrict__ v, __half* __restrict__ vt)
{
    const int tid = blockIdx.x * blockDim.x + threadIdx.x;
    if (tid >= BATCH * HW) return;
    const int b = tid / HW;
    const int p = tid - b * HW;

    const float* src = v + (size_t)b * CHAN * HW + p;

    __half2 d[8];
#pragma unroll
    for (int j = 0; j < 8; ++j) {
        const float lo = __builtin_nontemporal_load(&src[(size_t)(2 * j + 0) * HW]);
        const float hi = __builtin_nontemporal_load(&src[(size_t)(2 * j + 1) * HW]);
        d[j] = __floats2half2_rn(lo, hi);
    }

    uint4* dst = (uint4*)(vt + (size_t)tid * CHAN);
    dst[0] = *(const uint4*)&d[0];
    dst[1] = *(const uint4*)&d[4];
}

// --- pass 2: gather + bilinear in f16 BHWC, f32 math, write BCHW -----------
__global__ __launch_bounds__(256) void interp2_bhwc_f16(
    const __half* __restrict__ vt,
    const float* __restrict__ xq,
    const float* __restrict__ yq,
    float* __restrict__ out)
{
    const int tid = blockIdx.x * blockDim.x + threadIdx.x;
    if (tid >= BATCH * HW) return;

    const int b   = tid / HW;
    const int pix = tid - b * HW;

    const float xqv = __builtin_nontemporal_load(&xq[tid]);
    const float yqv = __builtin_nontemporal_load(&yq[tid]);

    const bool invalid = (xqv < 0.0f) | (xqv >= (float)WIDTH) |
                         (yqv < 0.0f) | (yqv >= (float)HEIGHT);

    int x0 = (int)floorf(xqv);
    int y0 = (int)floorf(yqv);
    x0 = min(max(x0, 0), WIDTH - 1);
    y0 = min(max(y0, 0), HEIGHT - 1);
    const int x1 = min(x0 + 1, WIDTH - 1);
    const int y1 = min(y0 + 1, HEIGHT - 1);

    const float dx = xqv - (float)x0;
    const float dy = yqv - (float)y0;

    float w00 = (1.0f - dy) * (1.0f - dx);
    float w01 = (1.0f - dy) * dx;
    float w10 = dy * (1.0f - dx);
    float w11 = dy * dx;
    if (invalid) { w00 = 0.0f; w01 = 0.0f; w10 = 0.0f; w11 = 0.0f; }

    const size_t bbase = (size_t)b * HW;

    float acc[CHAN];
#pragma unroll
    for (int c = 0; c < CHAN; ++c) acc[c] = 0.0f;

    auto corner = [&](int y, int x, float w) {
        const __half* p = vt + (bbase + (size_t)y * WIDTH + x) * CHAN;
        const uint4 a0 = *(const uint4*)p;         // halves 0..7 (cached)
        const uint4 a1 = *(const uint4*)(p + 8);   // halves 8..15
        const __half2* h0 = (const __half2*)&a0;
        const __half2* h1 = (const __half2*)&a1;
#pragma unroll
        for (int j = 0; j < 4; ++j) {
            const float2 f = __half22float2(h0[j]);
            acc[2 * j + 0] += w * f.x;
            acc[2 * j + 1] += w * f.y;
        }
#pragma unroll
        for (int j = 0; j < 4; ++j) {
            const float2 f = __half22float2(h1[j]);
            acc[8 + 2 * j + 0] += w * f.x;
            acc[8 + 2 * j + 1] += w * f.y;
        }
    };

    corner(y0, x0, w00);
    corner(y0, x1, w01);
    corner(y1, x0, w10);
    corner(y1, x1, w11);

    // BCHW output: per-c stores coalesced across lanes; non-temporal so the
    // 131 MB write stream doesn't evict vt from L2.
    const size_t obase = (size_t)b * CHAN * HW + pix;
#pragma unroll
    for (int c = 0; c < CHAN; ++c)
        __builtin_nontemporal_store(acc[c], &out[obase + (size_t)c * HW]);
}

// --- fallback (BCHW direct) if ws too small --------------------------------
__global__ __launch_bounds__(256) void interp2_bchw(
    const float* __restrict__ v,
    const float* __restrict__ xq,
    const float* __restrict__ yq,
    float* __restrict__ out)
{
    const int tid = blockIdx.x * blockDim.x + threadIdx.x;
    if (tid >= BATCH * HW) return;

    const int b   = tid / HW;
    const int pix = tid - b * HW;

    const float xqv = xq[tid];
    const float yqv = yq[tid];
    const bool invalid = (xqv < 0.0f) | (xqv >= (float)WIDTH) |
                         (yqv < 0.0f) | (yqv >= (float)HEIGHT);

    int x0 = (int)floorf(xqv);
    int y0 = (int)floorf(yqv);
    x0 = min(max(x0, 0), WIDTH - 1);
    y0 = min(max(y0, 0), HEIGHT - 1);
    const int x1 = min(x0 + 1, WIDTH - 1);
    const int y1 = min(y0 + 1, HEIGHT - 1);

    const float dx = xqv - (float)x0;
    const float dy = yqv - (float)y0;
    float w00 = (1.0f - dy) * (1.0f - dx);
    float w01 = (1.0f - dy) * dx;
    float w10 = dy * (1.0f - dx);
    float w11 = dy * dx;
    if (invalid) { w00 = 0.0f; w01 = 0.0f; w10 = 0.0f; w11 = 0.0f; }

    const int off00 = y0 * WIDTH + x0;
    const int off01 = y0 * WIDTH + x1;
    const int off10 = y1 * WIDTH + x0;
    const int off11 = y1 * WIDTH + x1;

    const int vbase = b * CHAN * HW;
    const int obase = vbase + pix;
#pragma unroll
    for (int c = 0; c < CHAN; ++c) {
        const int cb = vbase + c * HW;
        out[obase + c * HW] = v[cb + off00] * w00 + v[cb + off01] * w01 +
                              v[cb + off10] * w10 + v[cb + off11] * w11;
    }
}

extern "C" void kernel_launch(void* const* d_in, const int* in_sizes, int n_in,
                              void* d_out, int out_size, void* d_ws, size_t ws_size,
                              hipStream_t stream) {
    const float* v  = (const float*)d_in[0];
    const float* xq = (const float*)d_in[1];
    const float* yq = (const float*)d_in[2];
    float* out = (float*)d_out;

    const int npix = BATCH * HW;
    const int block = 256;
    const int grid = (npix + block - 1) / block;

    const size_t vt_bytes = (size_t)BATCH * HW * CHAN * sizeof(__half);  // 64 MiB
    if (ws_size >= vt_bytes) {
        __half* vt = (__half*)d_ws;
        transpose_bchw2bhwc_f16<<<grid, block, 0, stream>>>(v, vt);
        interp2_bhwc_f16<<<grid, block, 0, stream>>>(vt, xq, yq, out);
    } else {
        interp2_bchw<<<grid, block, 0, stream>>>(v, xq, yq, out);
    }
}